// Round 3
// baseline (202.412 us; speedup 1.0000x reference)
//
#include <hip/hip_runtime.h>
#include <hip/hip_bf16.h>

#define ENC 2048
#define ADIM 512
#define DEC 512
#define NBATCH 128
#define NL 196
#define MTOT (NBATCH * NL)   // 25088
#define KT 64                // K-steps of 32

typedef __attribute__((ext_vector_type(8))) short short8;
typedef __attribute__((ext_vector_type(4))) float f32x4;

__device__ __forceinline__ unsigned short f2bf(float f) {
    __hip_bfloat16 h = __float2bfloat16(f);
    union { __hip_bfloat16 h; unsigned short u; } cv; cv.h = h; return cv.u;
}
__device__ __forceinline__ unsigned int f2bf2(float lo, float hi) {
    __hip_bfloat162 h = __float22bfloat162_rn(float2{lo, hi});
    union { __hip_bfloat162 h; unsigned int u; } cv; cv.h = h; return cv.u;
}

// async global -> LDS, 16B per lane. lds pointer must be wave-uniform.
__device__ __forceinline__ void load_lds16(const void* g, void* l) {
    __builtin_amdgcn_global_load_lds(
        (const __attribute__((address_space(1))) unsigned int*)g,
        (__attribute__((address_space(3))) unsigned int*)l, 16, 0, 0);
}

// ---------------- kernel 1: w_ah = hidden @ W_w + W_b  [128 x 512] ----------------
__global__ void wah_kernel(const float* __restrict__ hidden, const float* __restrict__ Ww,
                           const float* __restrict__ Wb, float* __restrict__ wah) {
    __shared__ __align__(16) float hs[DEC];
    const int b = blockIdx.x, a = threadIdx.x;   // block 512 threads
    hs[a] = hidden[b * DEC + a];
    __syncthreads();
    float acc = Wb[a];
    #pragma unroll 4
    for (int d = 0; d < DEC; d += 4) {
        f32x4 h = *(const f32x4*)&hs[d];
        acc += h.x * Ww[(d    ) * ADIM + a];
        acc += h.y * Ww[(d + 1) * ADIM + a];
        acc += h.z * Ww[(d + 2) * ADIM + a];
        acc += h.w * Ww[(d + 3) * ADIM + a];
    }
    wah[b * ADIM + a] = acc;
}

// ---------------- kernel 2: U_w [K=2048][N=512] fp32 -> uwT [N][K] bf16 ----------------
__global__ void transpose_uw(const float* __restrict__ Uw, unsigned short* __restrict__ uwT) {
    __shared__ float t[32][33];
    const int k0 = blockIdx.x * 32, n0 = blockIdx.y * 32;
    const int tx = threadIdx.x, ty = threadIdx.y;   // 32 x 8
    #pragma unroll
    for (int i = 0; i < 4; ++i)
        t[ty + 8 * i][tx] = Uw[(size_t)(k0 + ty + 8 * i) * ADIM + n0 + tx];
    __syncthreads();
    #pragma unroll
    for (int i = 0; i < 4; ++i)
        uwT[(size_t)(n0 + ty + 8 * i) * ENC + k0 + tx] = f2bf(t[tx][ty + 8 * i]);
}

// ---------------- kernel 3: fused GEMM + tanh + A_w-dot -> score partials ----------------
// 2-phase pipelined (T3-minimum): STAGE(t+1) issued BEFORE compute(t); one
// vmcnt-drain barrier per K-step. BK=32, double-buffered 48KB LDS, 3 blocks/CU.
// A [128 r][32 k] fp32, swizzle byte ^= (r&7)<<4 (128B rows).
// B [128 n][32 k] bf16, swizzle byte ^= ((n&3)<<4)^((n&4)<<2) (64B rows).
// Swizzles applied on the GLOBAL SOURCE address (LDS dest linear) and on reads.
__global__ __launch_bounds__(256, 3) void gemm_score_kernel(
    const float* __restrict__ feat, const unsigned short* __restrict__ uwT,
    const float* __restrict__ Ub, const float* __restrict__ wahb,
    const float* __restrict__ Aw, float* __restrict__ part)
{
    __shared__ __align__(16) unsigned char As[2][16384];  // fp32, swizzled
    __shared__ __align__(16) unsigned char Bs[2][8192];   // bf16, swizzled

    const int tid  = threadIdx.x;
    const int lane = tid & 63;
    const int w    = tid >> 6;
    const int wr   = w >> 1, wc = w & 1;
    const int l15  = lane & 15, ldr = lane >> 4;

    // bijective XCD swizzle: 784 blocks = 8 XCD chunks of 98 (nbk-fastest -> 4 nbk share A-panel in L2)
    const int bid  = blockIdx.x;
    const int work = (bid & 7) * 98 + (bid >> 3);
    const int mb   = work >> 2;    // 0..195
    const int nbk  = work & 3;     // 0..3

    // ---- DMA source pointers (pre-swizzled global addresses) ----
    const char* featb = (const char*)feat;
    const char* uwTb  = (const char*)uwT;
    // A: 4 chunks/wave, chunk c = rows w*32+c*8 .. +7; lane fills row (lane>>3), bytes (lane&7)*16
    const char* aSrc[4];
    {
        const int innerA = ((lane & 7) * 16) ^ ((lane >> 3) << 4);   // (r&7) == lane>>3
        #pragma unroll
        for (int c = 0; c < 4; ++c) {
            const int row = w * 32 + c * 8 + (lane >> 3);
            aSrc[c] = featb + (size_t)(mb * 128 + row) * (ENC * 4) + innerA;
        }
    }
    // B: 2 chunks/wave, chunk c = rows w*32+c*16 .. +15; lane fills row (lane>>2), bytes (lane&3)*16
    const char* bSrc[2];
    {
        const int nn = (lane >> 2) & 7;                              // (n&7) == (lane>>2)&7
        const int innerB = ((lane & 3) * 16) ^ ((nn & 3) << 4) ^ ((nn & 4) << 2);
        #pragma unroll
        for (int c = 0; c < 2; ++c) {
            const int n = w * 32 + c * 16 + (lane >> 2);
            bSrc[c] = uwTb + (size_t)(nbk * 128 + n) * (ENC * 2) + innerB;
        }
    }

    // ---- fragment read byte offsets (same swizzles) ----
    int abyte[4][2], bbyte[4];
    #pragma unroll
    for (int f = 0; f < 4; ++f) {
        const int r  = wr * 64 + f * 16 + l15;
        const int n  = wc * 64 + f * 16 + l15;
        const int rs = (l15 & 7) << 4;
        abyte[f][0] = r * 128 + ((ldr * 32)      ^ rs);
        abyte[f][1] = r * 128 + ((ldr * 32 + 16) ^ rs);
        bbyte[f]    = n * 64  + ((ldr * 16) ^ ((l15 & 3) << 4) ^ ((l15 & 4) << 2));
    }

    f32x4 acc[4][4];
    #pragma unroll
    for (int i = 0; i < 4; ++i)
        #pragma unroll
        for (int j = 0; j < 4; ++j)
            acc[i][j] = (f32x4){0.f, 0.f, 0.f, 0.f};

#define STAGE(KTI, BB) {                                                         \
    _Pragma("unroll")                                                            \
    for (int c = 0; c < 4; ++c)                                                  \
        load_lds16(aSrc[c] + (size_t)(KTI) * 128, &As[BB][w * 4096 + c * 1024]); \
    _Pragma("unroll")                                                            \
    for (int c = 0; c < 2; ++c)                                                  \
        load_lds16(bSrc[c] + (size_t)(KTI) * 64,  &Bs[BB][w * 2048 + c * 1024]); \
}
#define COMPUTE(BB) {                                                            \
    short8 af[4], bf[4];                                                         \
    _Pragma("unroll")                                                            \
    for (int f = 0; f < 4; ++f) {                                                \
        f32x4 lo = *(const f32x4*)(As[BB] + abyte[f][0]);                        \
        f32x4 hi = *(const f32x4*)(As[BB] + abyte[f][1]);                        \
        union { unsigned int u[4]; short8 s; } cv;                               \
        cv.u[0] = f2bf2(lo.x, lo.y);                                             \
        cv.u[1] = f2bf2(lo.z, lo.w);                                             \
        cv.u[2] = f2bf2(hi.x, hi.y);                                             \
        cv.u[3] = f2bf2(hi.z, hi.w);                                             \
        af[f] = cv.s;                                                            \
        bf[f] = *(const short8*)(Bs[BB] + bbyte[f]);                             \
    }                                                                            \
    _Pragma("unroll")                                                            \
    for (int fm = 0; fm < 4; ++fm)                                               \
        _Pragma("unroll")                                                        \
        for (int fn = 0; fn < 4; ++fn)                                           \
            acc[fm][fn] = __builtin_amdgcn_mfma_f32_16x16x32_bf16(               \
                af[fm], bf[fn], acc[fm][fn], 0, 0, 0);                           \
}

    STAGE(0, 0);
    __syncthreads();
    #pragma unroll 1
    for (int kt = 0; kt < KT; kt += 2) {
        // phase 0: prefetch kt+1 into buf1, compute buf0
        if (kt + 1 < KT) STAGE(kt + 1, 1);
        COMPUTE(0);
        __syncthreads();          // drains vmcnt -> buf1 ready; buf0 free
        // phase 1: prefetch kt+2 into buf0, compute buf1
        if (kt + 2 < KT) STAGE(kt + 2, 0);
        COMPUTE(1);
        __syncthreads();
    }
#undef STAGE
#undef COMPUTE

    // epilogue: score partial = sum_c Aw[c] * tanh(acc + Ub[c] + wah[b][c]) over this block's 128 cols
    float ub4[4], aw4[4]; int cidx[4];
    #pragma unroll
    for (int f = 0; f < 4; ++f) {
        const int c = nbk * 128 + wc * 64 + f * 16 + l15;
        cidx[f] = c; ub4[f] = Ub[c]; aw4[f] = Aw[c];
    }
    #pragma unroll
    for (int fm = 0; fm < 4; ++fm) {
        #pragma unroll
        for (int r = 0; r < 4; ++r) {
            const int m = mb * 128 + wr * 64 + fm * 16 + ldr * 4 + r;
            const int b = m / NL;
            const float* wrow = wahb + b * ADIM;
            float s = 0.f;
            #pragma unroll
            for (int f = 0; f < 4; ++f)
                s += aw4[f] * tanhf(acc[fm][f][r] + ub4[f] + wrow[cidx[f]]);
            s += __shfl_xor(s, 1);
            s += __shfl_xor(s, 2);
            s += __shfl_xor(s, 4);
            s += __shfl_xor(s, 8);
            if (l15 == 0) part[(nbk * 2 + wc) * MTOT + m] = s;
        }
    }
}

// ---------------- kernel 4: reduce partials + softmax over L -> alpha ----------------
__global__ void softmax_kernel(const float* __restrict__ part, const float* __restrict__ Ab,
                               float* __restrict__ alpha) {
    const int b = blockIdx.x, t = threadIdx.x;   // 256 threads
    float sv = 0.f;
    if (t < NL) {
        sv = Ab[0];
        #pragma unroll
        for (int p = 0; p < 8; ++p) sv += part[p * MTOT + b * NL + t];
    }
    float v = (t < NL) ? sv : -3.4e38f;
    #pragma unroll
    for (int o = 32; o >= 1; o >>= 1) v = fmaxf(v, __shfl_xor(v, o));
    __shared__ float rm[4], rs[4];
    if ((t & 63) == 0) rm[t >> 6] = v;
    __syncthreads();
    const float bm = fmaxf(fmaxf(rm[0], rm[1]), fmaxf(rm[2], rm[3]));
    const float e = (t < NL) ? expf(sv - bm) : 0.f;
    float s = e;
    #pragma unroll
    for (int o = 32; o >= 1; o >>= 1) s += __shfl_xor(s, o);
    if ((t & 63) == 0) rs[t >> 6] = s;
    __syncthreads();
    const float bs = rs[0] + rs[1] + rs[2] + rs[3];
    if (t < NL) alpha[b * NL + t] = e / bs;
}

// ---------------- kernel 5: context[b][e] = sum_l alpha[b][l] * feat[b][l][e] ----------------
__global__ void context_kernel(const float* __restrict__ feat, const float* __restrict__ alpha,
                               float* __restrict__ ctx) {
    __shared__ float al[NL];
    const int b = blockIdx.x, chunk = blockIdx.y, t = threadIdx.x;  // 128 threads
    for (int i = t; i < NL; i += 128) al[i] = alpha[b * NL + i];
    __syncthreads();
    const int e0 = chunk * 512 + t * 4;
    const float* fp = feat + (size_t)b * NL * ENC + e0;
    f32x4 acc0 = (f32x4){0.f, 0.f, 0.f, 0.f};
    f32x4 acc1 = (f32x4){0.f, 0.f, 0.f, 0.f};
    #pragma unroll 2
    for (int l = 0; l < NL; l += 2) {
        f32x4 f0 = *(const f32x4*)(fp + (size_t)l * ENC);
        f32x4 f1 = *(const f32x4*)(fp + (size_t)(l + 1) * ENC);
        acc0 += al[l] * f0;
        acc1 += al[l + 1] * f1;
    }
    f32x4 rsum = acc0 + acc1;
    *(f32x4*)(ctx + (size_t)b * ENC + e0) = rsum;
}

extern "C" void kernel_launch(void* const* d_in, const int* in_sizes, int n_in,
                              void* d_out, int out_size, void* d_ws, size_t ws_size,
                              hipStream_t stream) {
    const float* feat   = (const float*)d_in[0];
    const float* hidden = (const float*)d_in[1];
    const float* Uw     = (const float*)d_in[2];
    const float* Ub     = (const float*)d_in[3];
    const float* Ww     = (const float*)d_in[4];
    const float* Wb     = (const float*)d_in[5];
    const float* Aw     = (const float*)d_in[6];
    const float* Ab     = (const float*)d_in[7];

    float* out   = (float*)d_out;
    float* alpha = out;              // [128*196]
    float* ctx   = out + MTOT;       // [128*2048]

    char* ws = (char*)d_ws;
    float*          wahb = (float*)ws;                                   // 256 KB
    unsigned short* uwT  = (unsigned short*)(ws + 262144);               // 2 MB
    float*          partb= (float*)(ws + 262144 + 2097152);              // 8*25088*4 = 784 KB

    wah_kernel<<<dim3(128), dim3(512), 0, stream>>>(hidden, Ww, Wb, wahb);
    transpose_uw<<<dim3(64, 16), dim3(32, 8), 0, stream>>>(Uw, uwT);
    gemm_score_kernel<<<dim3(784), dim3(256), 0, stream>>>(feat, uwT, Ub, wahb, Aw, partb);
    softmax_kernel<<<dim3(128), dim3(256), 0, stream>>>(partb, Ab, alpha);
    context_kernel<<<dim3(128, 4), dim3(128), 0, stream>>>(feat, alpha, ctx);
}

// Round 4
// 176.806 us; speedup vs baseline: 1.1448x; 1.1448x over previous
//
#include <hip/hip_runtime.h>
#include <hip/hip_bf16.h>

#define ENC 2048
#define ADIM 512
#define DEC 512
#define NBATCH 128
#define NL 196
#define MTOT (NBATCH * NL)   // 25088
#define NKT 64               // K-steps of 32

typedef __attribute__((ext_vector_type(8))) short short8;
typedef __attribute__((ext_vector_type(4))) float f32x4;
typedef __attribute__((ext_vector_type(4))) unsigned int u32x4;

__device__ __forceinline__ unsigned short f2bf(float f) {
    __hip_bfloat16 h = __float2bfloat16(f);
    union { __hip_bfloat16 h; unsigned short u; } cv; cv.h = h; return cv.u;
}
__device__ __forceinline__ unsigned int f2bf2(float lo, float hi) {
    __hip_bfloat162 h = __float22bfloat162_rn(float2{lo, hi});
    union { __hip_bfloat162 h; unsigned int u; } cv; cv.h = h; return cv.u;
}

// async global -> LDS, 16B per lane. lds pointer must be wave-uniform.
__device__ __forceinline__ void load_lds16(const void* g, void* l) {
    __builtin_amdgcn_global_load_lds(
        (const __attribute__((address_space(1))) unsigned int*)g,
        (__attribute__((address_space(3))) unsigned int*)l, 16, 0, 0);
}

// ---------------- kernel 1: w_ah = hidden @ W_w + W_b  [128 x 512] ----------------
__global__ void wah_kernel(const float* __restrict__ hidden, const float* __restrict__ Ww,
                           const float* __restrict__ Wb, float* __restrict__ wah) {
    __shared__ __align__(16) float hs[DEC];
    const int b = blockIdx.x, a = threadIdx.x;   // block 512 threads
    hs[a] = hidden[b * DEC + a];
    __syncthreads();
    float acc = Wb[a];
    #pragma unroll 4
    for (int d = 0; d < DEC; d += 4) {
        f32x4 h = *(const f32x4*)&hs[d];
        acc += h.x * Ww[(d    ) * ADIM + a];
        acc += h.y * Ww[(d + 1) * ADIM + a];
        acc += h.z * Ww[(d + 2) * ADIM + a];
        acc += h.w * Ww[(d + 3) * ADIM + a];
    }
    wah[b * ADIM + a] = acc;
}

// ---------------- kernel 2: U_w [K=2048][N=512] fp32 -> uwT [N][K] bf16 ----------------
__global__ void transpose_uw(const float* __restrict__ Uw, unsigned short* __restrict__ uwT) {
    __shared__ float t[32][33];
    const int k0 = blockIdx.x * 32, n0 = blockIdx.y * 32;
    const int tx = threadIdx.x, ty = threadIdx.y;   // 32 x 8
    #pragma unroll
    for (int i = 0; i < 4; ++i)
        t[ty + 8 * i][tx] = Uw[(size_t)(k0 + ty + 8 * i) * ADIM + n0 + tx];
    __syncthreads();
    #pragma unroll
    for (int i = 0; i < 4; ++i)
        uwT[(size_t)(n0 + ty + 8 * i) * ENC + k0 + tx] = f2bf(t[tx][ty + 8 * i]);
}

// ---------------- kernel 3: fused GEMM + tanh + A_w-dot -> score partials ----------------
// Counted-vmcnt pipeline: A reg-staged (global->reg->cvt bf16->ds_write),
// B via global_load_lds DMA. FOUR separately-named LDS buffers so alias
// analysis can prove DMA writes don't alias current ds_reads (no auto vmcnt(0)).
// A/B LDS tiles [128 rows][32 k] bf16, 64B rows, swizzle: slot ^= (row>>1)&3.
// Steady state: A(t+1),A(t+2) in reg-flight, B(t+1) in DMA-flight => vmcnt(10).
__global__ __launch_bounds__(256, 3) void gemm_score_kernel(
    const float* __restrict__ feat, const unsigned short* __restrict__ uwT,
    const float* __restrict__ Ub, const float* __restrict__ wahb,
    const float* __restrict__ Aw, float* __restrict__ part)
{
    __shared__ __align__(16) unsigned char Ab0[8192];
    __shared__ __align__(16) unsigned char Ab1[8192];
    __shared__ __align__(16) unsigned char Bb0[8192];
    __shared__ __align__(16) unsigned char Bb1[8192];

    const int tid  = threadIdx.x;
    const int lane = tid & 63;
    const int w    = tid >> 6;
    const int wr   = w >> 1, wc = w & 1;
    const int l15  = lane & 15, ldr = lane >> 4;

    // bijective XCD swizzle: 784 blocks = 8 XCD chunks of 98 (nbk fastest -> 4 nbk share A-panel in L2)
    const int bid  = blockIdx.x;
    const int work = (bid & 7) * 98 + (bid >> 3);
    const int mb   = work >> 2;    // 0..195
    const int nbk  = work & 3;     // 0..3

    // ---- A global source: thread -> row tid>>1, half tid&1 (64B = 4 x f32x4) ----
    const int r_ = tid >> 1, h_ = tid & 1;
    const float* aSrc = feat + (size_t)(mb * 128 + r_) * ENC + h_ * 16;
    // ---- A ds_write offsets (swizzled) ----
    const int xw = (r_ >> 1) & 3;
    const int wA0 = r_ * 64 + (((h_ * 2 + 0) ^ xw) << 4);
    const int wA1 = r_ * 64 + (((h_ * 2 + 1) ^ xw) << 4);

    // ---- B DMA source (pre-swizzled global addr); dest wave-uniform linear ----
    const unsigned short* bSrc = uwT
        + (size_t)(nbk * 128 + w * 32 + (lane >> 2)) * ENC
        + ((lane & 3) ^ ((lane >> 3) & 3)) * 8;

    // ---- fragment read byte offsets ----
    const int xr = (l15 >> 1) & 3;
    int abyte[4], bbyte[4];
    #pragma unroll
    for (int f = 0; f < 4; ++f) {
        const int r = wr * 64 + f * 16 + l15;
        const int n = wc * 64 + f * 16 + l15;
        abyte[f] = r * 64 + ((ldr ^ xr) << 4);
        bbyte[f] = n * 64 + ((ldr ^ xr) << 4);
    }

    f32x4 acc[4][4];
    #pragma unroll
    for (int i = 0; i < 4; ++i)
        #pragma unroll
        for (int j = 0; j < 4; ++j)
            acc[i][j] = (f32x4){0.f, 0.f, 0.f, 0.f};

    f32x4 a00, a01, a02, a03;   // A(t) regs, even phases
    f32x4 a10, a11, a12, a13;   // A(t) regs, odd phases

#define ISSUE_A(KTI, R0, R1, R2, R3) {                                  \
    const f32x4* p = (const f32x4*)(aSrc + (size_t)(KTI) * 32);         \
    R0 = p[0]; R1 = p[1]; R2 = p[2]; R3 = p[3];                         \
    __builtin_amdgcn_sched_barrier(0);                                  \
}
#define ISSUE_B(KTI, BB) {                                              \
    load_lds16(bSrc + (size_t)(KTI) * 32,            (BB) + w * 2048);  \
    load_lds16(bSrc + 16 * ENC + (size_t)(KTI) * 32, (BB) + w * 2048 + 1024); \
    __builtin_amdgcn_sched_barrier(0);                                  \
}
#define CVT_WRITE(R0, R1, R2, R3, AB) {                                 \
    u32x4 w0, w1;                                                       \
    w0.x = f2bf2(R0.x, R0.y); w0.y = f2bf2(R0.z, R0.w);                 \
    w0.z = f2bf2(R1.x, R1.y); w0.w = f2bf2(R1.z, R1.w);                 \
    w1.x = f2bf2(R2.x, R2.y); w1.y = f2bf2(R2.z, R2.w);                 \
    w1.z = f2bf2(R3.x, R3.y); w1.w = f2bf2(R3.z, R3.w);                 \
    *(u32x4*)((AB) + wA0) = w0;                                         \
    *(u32x4*)((AB) + wA1) = w1;                                         \
}
#define COMPUTE(AB, BB) {                                               \
    short8 af[4], bf[4];                                                \
    _Pragma("unroll")                                                   \
    for (int f = 0; f < 4; ++f) {                                       \
        af[f] = *(const short8*)((AB) + abyte[f]);                      \
        bf[f] = *(const short8*)((BB) + bbyte[f]);                      \
    }                                                                   \
    _Pragma("unroll")                                                   \
    for (int fm = 0; fm < 4; ++fm)                                      \
        _Pragma("unroll")                                               \
        for (int fn = 0; fn < 4; ++fn)                                  \
            acc[fm][fn] = __builtin_amdgcn_mfma_f32_16x16x32_bf16(      \
                af[fm], bf[fn], acc[fm][fn], 0, 0, 0);                  \
}
#define PHASE(T2, RA0, RA1, RA2, RA3, AB, BB) {                         \
    CVT_WRITE(RA0, RA1, RA2, RA3, AB);                                  \
    ISSUE_A(T2, RA0, RA1, RA2, RA3);                                    \
    asm volatile("s_waitcnt vmcnt(10)");                                \
    __builtin_amdgcn_sched_barrier(0);                                  \
    asm volatile("s_waitcnt lgkmcnt(0)");                               \
    __builtin_amdgcn_sched_barrier(0);                                  \
    __builtin_amdgcn_s_barrier();                                       \
    COMPUTE(AB, BB);                                                    \
    __builtin_amdgcn_s_barrier();                                       \
    ISSUE_B(T2, BB);                                                    \
}

    // prologue: issue order A(0), B(0), A(1), B(1)
    ISSUE_A(0, a00, a01, a02, a03);
    ISSUE_B(0, Bb0);
    ISSUE_A(1, a10, a11, a12, a13);
    ISSUE_B(1, Bb1);

    #pragma unroll 1
    for (int kt = 0; kt < NKT; kt += 2) {
        const int k2 = (kt + 2 < NKT) ? kt + 2 : NKT - 1;
        const int k3 = (kt + 3 < NKT) ? kt + 3 : NKT - 1;
        PHASE(k2, a00, a01, a02, a03, Ab0, Bb0);
        PHASE(k3, a10, a11, a12, a13, Ab1, Bb1);
    }
#undef ISSUE_A
#undef ISSUE_B
#undef CVT_WRITE
#undef COMPUTE
#undef PHASE

    // epilogue: score partial = sum_c Aw[c] * tanh(acc + Ub[c] + wah[b][c]) over this block's 128 cols
    float ub4[4], aw4[4]; int cidx[4];
    #pragma unroll
    for (int f = 0; f < 4; ++f) {
        const int c = nbk * 128 + wc * 64 + f * 16 + l15;
        cidx[f] = c; ub4[f] = Ub[c]; aw4[f] = Aw[c];
    }
    #pragma unroll
    for (int fm = 0; fm < 4; ++fm) {
        #pragma unroll
        for (int r = 0; r < 4; ++r) {
            const int m = mb * 128 + wr * 64 + fm * 16 + ldr * 4 + r;
            const int b = m / NL;
            const float* wrow = wahb + b * ADIM;
            float s = 0.f;
            #pragma unroll
            for (int f = 0; f < 4; ++f)
                s += aw4[f] * tanhf(acc[fm][f][r] + ub4[f] + wrow[cidx[f]]);
            s += __shfl_xor(s, 1);
            s += __shfl_xor(s, 2);
            s += __shfl_xor(s, 4);
            s += __shfl_xor(s, 8);
            if (l15 == 0) part[(nbk * 2 + wc) * MTOT + m] = s;
        }
    }
}

// ---------------- kernel 4: reduce partials + softmax over L -> alpha ----------------
__global__ void softmax_kernel(const float* __restrict__ part, const float* __restrict__ Ab,
                               float* __restrict__ alpha) {
    const int b = blockIdx.x, t = threadIdx.x;   // 256 threads
    float sv = 0.f;
    if (t < NL) {
        sv = Ab[0];
        #pragma unroll
        for (int p = 0; p < 8; ++p) sv += part[p * MTOT + b * NL + t];
    }
    float v = (t < NL) ? sv : -3.4e38f;
    #pragma unroll
    for (int o = 32; o >= 1; o >>= 1) v = fmaxf(v, __shfl_xor(v, o));
    __shared__ float rm[4], rs[4];
    if ((t & 63) == 0) rm[t >> 6] = v;
    __syncthreads();
    const float bm = fmaxf(fmaxf(rm[0], rm[1]), fmaxf(rm[2], rm[3]));
    const float e = (t < NL) ? expf(sv - bm) : 0.f;
    float s = e;
    #pragma unroll
    for (int o = 32; o >= 1; o >>= 1) s += __shfl_xor(s, o);
    if ((t & 63) == 0) rs[t >> 6] = s;
    __syncthreads();
    const float bs = rs[0] + rs[1] + rs[2] + rs[3];
    if (t < NL) alpha[b * NL + t] = e / bs;
}

// ---------------- kernel 5: context[b][e] = sum_l alpha[b][l] * feat[b][l][e] ----------------
__global__ void context_kernel(const float* __restrict__ feat, const float* __restrict__ alpha,
                               float* __restrict__ ctx) {
    __shared__ float al[NL];
    const int b = blockIdx.x, chunk = blockIdx.y, t = threadIdx.x;  // 128 threads
    for (int i = t; i < NL; i += 128) al[i] = alpha[b * NL + i];
    __syncthreads();
    const int e0 = chunk * 512 + t * 4;
    const float* fp = feat + (size_t)b * NL * ENC + e0;
    f32x4 acc0 = (f32x4){0.f, 0.f, 0.f, 0.f};
    f32x4 acc1 = (f32x4){0.f, 0.f, 0.f, 0.f};
    #pragma unroll 2
    for (int l = 0; l < NL; l += 2) {
        f32x4 f0 = *(const f32x4*)(fp + (size_t)l * ENC);
        f32x4 f1 = *(const f32x4*)(fp + (size_t)(l + 1) * ENC);
        acc0 += al[l] * f0;
        acc1 += al[l + 1] * f1;
    }
    f32x4 rsum = acc0 + acc1;
    *(f32x4*)(ctx + (size_t)b * ENC + e0) = rsum;
}

extern "C" void kernel_launch(void* const* d_in, const int* in_sizes, int n_in,
                              void* d_out, int out_size, void* d_ws, size_t ws_size,
                              hipStream_t stream) {
    const float* feat   = (const float*)d_in[0];
    const float* hidden = (const float*)d_in[1];
    const float* Uw     = (const float*)d_in[2];
    const float* Ub     = (const float*)d_in[3];
    const float* Ww     = (const float*)d_in[4];
    const float* Wb     = (const float*)d_in[5];
    const float* Aw     = (const float*)d_in[6];
    const float* Ab     = (const float*)d_in[7];

    float* out   = (float*)d_out;
    float* alpha = out;              // [128*196]
    float* ctx   = out + MTOT;       // [128*2048]

    char* ws = (char*)d_ws;
    float*          wahb = (float*)ws;                                   // 256 KB
    unsigned short* uwT  = (unsigned short*)(ws + 262144);               // 2 MB
    float*          partb= (float*)(ws + 262144 + 2097152);              // 8*25088*4 = 784 KB

    wah_kernel<<<dim3(128), dim3(512), 0, stream>>>(hidden, Ww, Wb, wahb);
    transpose_uw<<<dim3(64, 16), dim3(32, 8), 0, stream>>>(Uw, uwT);
    gemm_score_kernel<<<dim3(784), dim3(256), 0, stream>>>(feat, uwT, Ub, wahb, Aw, partb);
    softmax_kernel<<<dim3(128), dim3(256), 0, stream>>>(partb, Ab, alpha);
    context_kernel<<<dim3(128, 4), dim3(128), 0, stream>>>(feat, alpha, ctx);
}